// Round 1
// baseline (61158.374 us; speedup 1.0000x reference)
//
#include <hip/hip_runtime.h>
#include <math.h>

#define SEQ   2048
#define BATCH 64
#define NIN   256
#define NHID  512
#define NOUT  128

#define GB    8                 // batch groups (8 batch each)
#define GJ    16                // hidden-unit groups (32 j each)
#define BPG   (BATCH/GB)        // 8
#define JPG   (NHID/GJ)         // 32

#define HBUF_FLOATS (2*NHID*BATCH)

// Persistent RNN kernel. 128 blocks = 8 batch-groups x 16 j-groups.
// Each block owns a (8 batch x 32 hidden) slice of h. W_ih/W_hh slices live
// in LDS for the whole 2048-step loop. Per-step sync is only among the 16
// blocks of one batch-group (monotonic counter barrier).
__global__ __launch_bounds__(256, 1)
void rnn_persist_kernel(const float* __restrict__ x,
                        const float* __restrict__ Wih,
                        const float* __restrict__ bih,
                        const float* __restrict__ Whh,
                        const float* __restrict__ bhh,
                        float* __restrict__ hbuf,
                        unsigned* __restrict__ bar)
{
  const int gj  = blockIdx.x >> 3;   // 0..15
  const int gb  = blockIdx.x & 7;    // 0..7
  const int tid = threadIdx.x;
  const int jl  = tid & 31;          // 0..31
  const int bl  = tid >> 5;          // 0..7
  const int j   = gj*JPG + jl;       // this thread's hidden unit
  const int b   = gb*BPG + bl;       // this thread's batch row

  // +1 pad: lane j reads Ws[j][k] -> bank (j*513+k)%32 = (j+k)%32, conflict-free
  __shared__ float Ws[JPG][NHID+1];  // 32 x 513 fp32 = 65.7 KB
  __shared__ float Wi[JPG][NIN+1];   // 32 x 257 fp32 = 32.9 KB

  for (int idx = tid; idx < JPG*NHID; idx += 256) {
    const int jj = idx >> 9, kk = idx & (NHID-1);
    Ws[jj][kk] = Whh[(size_t)(gj*JPG + jj)*NHID + kk];
  }
  for (int idx = tid; idx < JPG*NIN; idx += 256) {
    const int jj = idx >> 8, kk = idx & (NIN-1);
    Wi[jj][kk] = Wih[(size_t)(gj*JPG + jj)*NIN + kk];
  }
  const float bias = bih[j] + bhh[j];
  __syncthreads();

  unsigned* cnt = bar + gb*32;   // one counter (own 128B line) per batch-group

  // x-projection for t=0 (h0 = 0, handled by zeroed hbuf)
  float accx;
  {
    const float* xr = x + (size_t)b*NIN;
    float c0=0.f,c1=0.f,c2=0.f,c3=0.f;
    #pragma unroll 4
    for (int k = 0; k < NIN; k += 4) {
      c0 = fmaf(Wi[jl][k  ], xr[k  ], c0);
      c1 = fmaf(Wi[jl][k+1], xr[k+1], c1);
      c2 = fmaf(Wi[jl][k+2], xr[k+2], c2);
      c3 = fmaf(Wi[jl][k+3], xr[k+3], c3);
    }
    accx = (c0+c1)+(c2+c3) + bias;
  }

  for (int t = 0; t < SEQ; ++t) {
    // recurrent projection: h stored transposed h[k][b]
    const float* hc = hbuf + (t & 1)*(NHID*BATCH) + b;
    float a0=0.f,a1=0.f,a2=0.f,a3=0.f;
    #pragma unroll 4
    for (int k = 0; k < NHID; k += 4) {
      a0 = fmaf(Ws[jl][k  ], hc[(k  )*BATCH], a0);
      a1 = fmaf(Ws[jl][k+1], hc[(k+1)*BATCH], a1);
      a2 = fmaf(Ws[jl][k+2], hc[(k+2)*BATCH], a2);
      a3 = fmaf(Ws[jl][k+3], hc[(k+3)*BATCH], a3);
    }
    const float hnew = tanhf(accx + (a0+a1)+(a2+a3));
    hbuf[((t+1)&1)*(NHID*BATCH) + j*BATCH + b] = hnew;

    // publish writes, then arrive at the batch-group barrier
    __threadfence();
    __syncthreads();
    if (tid == 0)
      __hip_atomic_fetch_add(cnt, 1u, __ATOMIC_RELEASE, __HIP_MEMORY_SCOPE_AGENT);

    // overlap barrier propagation with next step's x-projection (h-independent)
    if (t + 1 < SEQ) {
      const float* xr = x + ((size_t)(t+1)*BATCH + b)*NIN;
      float c0=0.f,c1=0.f,c2=0.f,c3=0.f;
      #pragma unroll 4
      for (int k = 0; k < NIN; k += 4) {
        c0 = fmaf(Wi[jl][k  ], xr[k  ], c0);
        c1 = fmaf(Wi[jl][k+1], xr[k+1], c1);
        c2 = fmaf(Wi[jl][k+2], xr[k+2], c2);
        c3 = fmaf(Wi[jl][k+3], xr[k+3], c3);
      }
      accx = (c0+c1)+(c2+c3) + bias;
    }

    if (tid == 0) {
      const unsigned target = (unsigned)(t+1) * GJ;  // 16 arrivals per step
      while (__hip_atomic_load(cnt, __ATOMIC_ACQUIRE, __HIP_MEMORY_SCOPE_AGENT) < target) {}
    }
    __syncthreads();
  }
}

// out[b][o] = h_final[:,b] . W_ho[o,:] + b_ho[o]; h_final is hbuf parity 0
__global__ __launch_bounds__(NOUT, 1)
void rnn_out_kernel(const float* __restrict__ hbuf,
                    const float* __restrict__ Who,
                    const float* __restrict__ bho,
                    float* __restrict__ out)
{
  const int b = blockIdx.x;    // 64 blocks
  const int o = threadIdx.x;   // 128 threads
  __shared__ float hL[NHID];
  for (int k = o; k < NHID; k += NOUT) hL[k] = hbuf[(size_t)k*BATCH + b];
  __syncthreads();
  const float* wr = Who + (size_t)o*NHID;
  float a0=0.f,a1=0.f,a2=0.f,a3=0.f;
  #pragma unroll 4
  for (int k = 0; k < NHID; k += 4) {
    a0 = fmaf(wr[k  ], hL[k  ], a0);
    a1 = fmaf(wr[k+1], hL[k+1], a1);
    a2 = fmaf(wr[k+2], hL[k+2], a2);
    a3 = fmaf(wr[k+3], hL[k+3], a3);
  }
  out[(size_t)b*NOUT + o] = (a0+a1)+(a2+a3) + bho[o];
}

extern "C" void kernel_launch(void* const* d_in, const int* in_sizes, int n_in,
                              void* d_out, int out_size, void* d_ws, size_t ws_size,
                              hipStream_t stream)
{
  const float* x   = (const float*)d_in[0];
  const float* Wih = (const float*)d_in[1];
  const float* bih = (const float*)d_in[2];
  const float* Whh = (const float*)d_in[3];
  const float* bhh = (const float*)d_in[4];
  const float* Who = (const float*)d_in[5];
  const float* bho = (const float*)d_in[6];
  float*   out  = (float*)d_out;
  float*   hbuf = (float*)d_ws;
  unsigned* bar = (unsigned*)((char*)d_ws + (size_t)HBUF_FLOATS*sizeof(float));

  // zero h (h0 = 0) and barrier counters every call -> deterministic replay
  hipMemsetAsync(d_ws, 0, (size_t)HBUF_FLOATS*sizeof(float) + GB*32*sizeof(unsigned), stream);

  rnn_persist_kernel<<<dim3(GB*GJ), dim3(256), 0, stream>>>(x, Wih, bih, Whh, bhh, hbuf, bar);
  rnn_out_kernel<<<dim3(BATCH), dim3(NOUT), 0, stream>>>(hbuf, Who, bho, out);
}

// Round 2
// 54739.648 us; speedup vs baseline: 1.1173x; 1.1173x over previous
//
#include <hip/hip_runtime.h>
#include <math.h>

#define SEQ   2048
#define BATCH 64
#define NIN   256
#define NHID  512
#define NOUT  128

#define GB 8                    // batch groups (8 batch rows each)
#define GJ 16                   // hidden groups (32 j each)
#define BPG (BATCH/GB)          // 8
#define JPG (NHID/GJ)           // 32

// LDS row pads: stride%32==4 -> bank=(4*row+k)&31, <=2-way (free); 16B aligned
#define WS_PAD 516
#define WI_PAD 260
#define HL_PAD 516

#define HBUF_FLOATS (2*NHID*BATCH)   // two parities of h, slice-major layout
#define FLAGS_PER_G 64               // u32 stride per batch-group (256B apart)

// h layout (per parity): slice (gj,gb) is contiguous:
//   hbuf[((gj*GB+gb)<<8) + jl*8 + bl]   (jl=0..31, bl=0..7)
// Producer writes its 1KB slice fully coalesced (4B/lane x 256 thr);
// consumer wave reads a slice as 64 x float4 (coalesced 1KB).

__global__ __launch_bounds__(256, 1)
void rnn_persist_kernel(const float* __restrict__ x,
                        const float* __restrict__ Wih,
                        const float* __restrict__ bih,
                        const float* __restrict__ Whh,
                        const float* __restrict__ bhh,
                        float* __restrict__ hbuf,
                        unsigned* __restrict__ flags)
{
  const int gj  = blockIdx.x >> 3;   // 0..15
  const int gb  = blockIdx.x & 7;    // 0..7
  const int tid = threadIdx.x;
  const int jl  = tid >> 3;          // 0..31  hidden unit within slice
  const int bl  = tid & 7;           // 0..7   batch row within group
  const int b   = gb*BPG + bl;

  __shared__ __align__(16) float Ws[JPG][WS_PAD];  // 66.0 KB
  __shared__ __align__(16) float Wi[JPG][WI_PAD];  // 33.3 KB
  __shared__ __align__(16) float hL[BPG][HL_PAD];  // 16.5 KB

  for (int idx = tid; idx < JPG*NHID; idx += 256) {
    const int jj = idx >> 9, kk = idx & (NHID-1);
    Ws[jj][kk] = Whh[(size_t)(gj*JPG + jj)*NHID + kk];
  }
  for (int idx = tid; idx < JPG*NIN; idx += 256) {
    const int jj = idx >> 8, kk = idx & (NIN-1);
    Wi[jj][kk] = Wih[(size_t)(gj*JPG + jj)*NIN + kk];
  }
  const float bias = bih[gj*JPG + jl] + bhh[gj*JPG + jl];
  __syncthreads();

  const int w    = tid >> 6;   // wave 0..3
  const int lane = tid & 63;
  unsigned* gflags = flags + gb*FLAGS_PER_G;

  // x-projection for t=0 (h0 = 0 via zeroed hbuf)
  float accx;
  {
    const float* xr = x + (size_t)b*NIN;
    float c0=0.f,c1=0.f,c2=0.f,c3=0.f;
    for (int k = 0; k < NIN; k += 4) {
      const float4 wv = *(const float4*)&Wi[jl][k];
      const float4 xv = *(const float4*)&xr[k];
      c0 = fmaf(wv.x, xv.x, c0); c1 = fmaf(wv.y, xv.y, c1);
      c2 = fmaf(wv.z, xv.z, c2); c3 = fmaf(wv.w, xv.w, c3);
    }
    accx = (c0+c1)+(c2+c3) + bias;
  }

  for (int t = 0; t < SEQ; ++t) {
    const float* hsrc = hbuf + (t & 1)*(NHID*BATCH);

    // arrival-pipelined staging: wave w owns source j-groups i=4w..4w+3.
    // Whole wave spins on one broadcast flag, then stages that 1KB slice.
    #pragma unroll
    for (int i2 = 0; i2 < 4; ++i2) {
      const int i = (w << 2) + i2;
      while (__hip_atomic_load(&gflags[i], __ATOMIC_ACQUIRE,
                               __HIP_MEMORY_SCOPE_AGENT) < (unsigned)t) {}
      const float4 v = *(const float4*)(hsrc + ((i*GB + gb) << 8) + (lane << 2));
      const int sj = (i << 5) + (lane >> 1);     // hidden index k
      const int sb = (lane & 1) << 2;            // batch sub-row base
      hL[sb+0][sj] = v.x;
      hL[sb+1][sj] = v.y;
      hL[sb+2][sj] = v.z;
      hL[sb+3][sj] = v.w;
    }
    __syncthreads();

    // recurrent dot from LDS (both operands ds_read_b128, conflict-free)
    float a0=0.f,a1=0.f,a2=0.f,a3=0.f;
    for (int k = 0; k < NHID; k += 4) {
      const float4 wv = *(const float4*)&Ws[jl][k];
      const float4 hv = *(const float4*)&hL[bl][k];
      a0 = fmaf(wv.x, hv.x, a0); a1 = fmaf(wv.y, hv.y, a1);
      a2 = fmaf(wv.z, hv.z, a2); a3 = fmaf(wv.w, hv.w, a3);
    }
    const float hnew = tanhf(accx + (a0+a1)+(a2+a3));

    // write own contiguous slice (fully coalesced 1KB per block)
    float* hdst = hbuf + ((t+1) & 1)*(NHID*BATCH);
    hdst[((gj*GB + gb) << 8) + (jl << 3) + bl] = hnew;

    __threadfence();        // each wave drains+publishes its own stores
    __syncthreads();
    if (tid == 0)
      __hip_atomic_store(&gflags[gj], (unsigned)(t+1), __ATOMIC_RELEASE,
                         __HIP_MEMORY_SCOPE_AGENT);

    // overlap remote-flag latency with next step's x-projection
    if (t + 1 < SEQ) {
      const float* xr = x + ((size_t)(t+1)*BATCH + b)*NIN;
      float c0=0.f,c1=0.f,c2=0.f,c3=0.f;
      for (int k = 0; k < NIN; k += 4) {
        const float4 wv = *(const float4*)&Wi[jl][k];
        const float4 xv = *(const float4*)&xr[k];
        c0 = fmaf(wv.x, xv.x, c0); c1 = fmaf(wv.y, xv.y, c1);
        c2 = fmaf(wv.z, xv.z, c2); c3 = fmaf(wv.w, xv.w, c3);
      }
      accx = (c0+c1)+(c2+c3) + bias;
    }
  }
}

// out[b][o] = h_final[:,b] . W_ho[o,:] + b_ho[o]; h_final in hbuf parity 0
__global__ __launch_bounds__(NOUT, 1)
void rnn_out_kernel(const float* __restrict__ hbuf,
                    const float* __restrict__ Who,
                    const float* __restrict__ bho,
                    float* __restrict__ out)
{
  const int b = blockIdx.x;    // 64
  const int o = threadIdx.x;   // 128
  __shared__ float hB[NHID];
  for (int k = o; k < NHID; k += NOUT)
    hB[k] = hbuf[(((k >> 5)*GB + (b >> 3)) << 8) + ((k & 31) << 3) + (b & 7)];
  __syncthreads();
  const float* wr = Who + (size_t)o*NHID;
  float a0=0.f,a1=0.f,a2=0.f,a3=0.f;
  for (int k = 0; k < NHID; k += 4) {
    const float4 wv = *(const float4*)&wr[k];
    a0 = fmaf(wv.x, hB[k  ], a0);
    a1 = fmaf(wv.y, hB[k+1], a1);
    a2 = fmaf(wv.z, hB[k+2], a2);
    a3 = fmaf(wv.w, hB[k+3], a3);
  }
  out[(size_t)b*NOUT + o] = (a0+a1)+(a2+a3) + bho[o];
}

extern "C" void kernel_launch(void* const* d_in, const int* in_sizes, int n_in,
                              void* d_out, int out_size, void* d_ws, size_t ws_size,
                              hipStream_t stream)
{
  const float* x   = (const float*)d_in[0];
  const float* Wih = (const float*)d_in[1];
  const float* bih = (const float*)d_in[2];
  const float* Whh = (const float*)d_in[3];
  const float* bhh = (const float*)d_in[4];
  const float* Who = (const float*)d_in[5];
  const float* bho = (const float*)d_in[6];
  float*    out   = (float*)d_out;
  float*    hbuf  = (float*)d_ws;
  unsigned* flags = (unsigned*)((char*)d_ws + (size_t)HBUF_FLOATS*sizeof(float));

  // zero h (h0=0) and flags every call -> deterministic graph replay
  hipMemsetAsync(d_ws, 0,
                 (size_t)HBUF_FLOATS*sizeof(float) + GB*FLAGS_PER_G*sizeof(unsigned),
                 stream);

  rnn_persist_kernel<<<dim3(GB*GJ), dim3(256), 0, stream>>>(
      x, Wih, bih, Whh, bhh, hbuf, flags);
  rnn_out_kernel<<<dim3(BATCH), dim3(NOUT), 0, stream>>>(hbuf, Who, bho, out);
}

// Round 3
// 23403.537 us; speedup vs baseline: 2.6132x; 2.3389x over previous
//
#include <hip/hip_runtime.h>
#include <math.h>

#define SEQ   2048
#define BATCH 64
#define NIN   256
#define NHID  512
#define NOUT  128

#define GB 8                    // batch groups (8 batch rows each)
#define GJ 16                   // hidden groups (32 j each)
#define BPG (BATCH/GB)          // 8
#define JPG (NHID/GJ)           // 32

// LDS pads: stride%32==4 -> banks spread, 16B-aligned rows
#define WS_PAD 516
#define WI_PAD 260
#define HL_PAD 516

// h wire format: float -> two u32 words, each (tag<<16)|half.
// slice (gj,gb) = 512 words: [0..255]=hi halves (float idx m=jl*8+bl),
// [256..511]=lo halves. Self-validating => NO fences/flags anywhere.
#define WORDS_PER_SLICE 512
#define WORDS_PER_PAR   (GJ*GB*WORDS_PER_SLICE)   // 65536
#define HBUF_WORDS      (2*WORDS_PER_PAR)          // 131072 (512 KB)

typedef unsigned int u32;
typedef u32 u32x4 __attribute__((ext_vector_type(4)));

__device__ __forceinline__ u32x4 ld_coh16(const u32* p) {
  u32x4 r;
  asm volatile("global_load_dwordx4 %0, %1, off sc0 sc1"
               : "=v"(r) : "v"(p) : "memory");
  return r;
}
__device__ __forceinline__ void wait_vm0() {
  asm volatile("s_waitcnt vmcnt(0)" ::: "memory");
  __builtin_amdgcn_sched_barrier(0);   // keep uses after the wait (rule #18)
}
__device__ __forceinline__ void st_coh4(u32* p, u32 v) {
  asm volatile("global_store_dword %0, %1, off sc0 sc1"
               :: "v"(p), "v"(v) : "memory");
}
__device__ __forceinline__ int tags8_ok(u32x4 a, u32x4 b, u32 t) {
  return (a.x>>16)==t && (a.y>>16)==t && (a.z>>16)==t && (a.w>>16)==t &&
         (b.x>>16)==t && (b.y>>16)==t && (b.z>>16)==t && (b.w>>16)==t;
}

__global__ __launch_bounds__(256, 1)
void rnn_persist_kernel(const float* __restrict__ x,
                        const float* __restrict__ Wih,
                        const float* __restrict__ bih,
                        const float* __restrict__ Whh,
                        const float* __restrict__ bhh,
                        u32* __restrict__ hw)
{
  const int gj  = blockIdx.x >> 3;   // 0..15
  const int gb  = blockIdx.x & 7;    // 0..7
  const int tid = threadIdx.x;
  const int jl  = tid >> 3;          // 0..31
  const int bl  = tid & 7;           // 0..7
  const int b   = gb*BPG + bl;
  const int w   = tid >> 6;          // wave 0..3
  const int lane= tid & 63;

  __shared__ __align__(16) float Ws[JPG][WS_PAD];    // 66.0 KB
  __shared__ __align__(16) float Wi[JPG][WI_PAD];    // 33.3 KB
  __shared__ __align__(16) float hL[2][BPG][HL_PAD]; // 33.0 KB

  for (int idx = tid; idx < JPG*NHID; idx += 256) {
    const int jj = idx >> 9, kk = idx & (NHID-1);
    Ws[jj][kk] = Whh[(size_t)(gj*JPG + jj)*NHID + kk];
  }
  for (int idx = tid; idx < JPG*NIN; idx += 256) {
    const int jj = idx >> 8, kk = idx & (NIN-1);
    Wi[jj][kk] = Wih[(size_t)(gj*JPG + jj)*NIN + kk];
  }
  const float bias = bih[gj*JPG + jl] + bhh[gj*JPG + jl];
  __syncthreads();

  // x-projection for t=0
  float accx;
  {
    const float* xr = x + (size_t)b*NIN;
    float c0=0.f,c1=0.f,c2=0.f,c3=0.f;
    for (int k = 0; k < NIN; k += 4) {
      const float4 wv = *(const float4*)&Wi[jl][k];
      const float4 xv = *(const float4*)&xr[k];
      c0 = fmaf(wv.x, xv.x, c0); c1 = fmaf(wv.y, xv.y, c1);
      c2 = fmaf(wv.z, xv.z, c2); c3 = fmaf(wv.w, xv.w, c3);
    }
    accx = (c0+c1)+(c2+c3) + bias;
  }

  for (int t = 0; t < SEQ; ++t) {
    const int par = t & 1;
    const u32 tg  = (u32)t;
    const u32* base = hw + par*WORDS_PER_PAR;

    // ---- stage h(t): wave w polls+copies slices 4w..4w+3 ----
    u32x4 A[4], B[4];
    const u32* pp[4];
    #pragma unroll
    for (int s = 0; s < 4; ++s) {
      const int i = (w << 2) + s;
      pp[s] = base + ((i*GB + gb) << 9) + (lane << 2);
      A[s] = ld_coh16(pp[s]);
      B[s] = ld_coh16(pp[s] + 256);
    }
    wait_vm0();
    #pragma unroll
    for (int s = 0; s < 4; ++s) {
      while (!__all(tags8_ok(A[s], B[s], tg))) {
        A[s] = ld_coh16(pp[s]);
        B[s] = ld_coh16(pp[s] + 256);
        wait_vm0();
      }
      const int i32 = ((w << 2) + s) << 5;
      const int m0  = lane << 2;
      hL[par][(m0  )&7][i32 + ((m0  )>>3)] = __uint_as_float((A[s].x<<16)|(B[s].x&0xffffu));
      hL[par][(m0+1)&7][i32 + ((m0+1)>>3)] = __uint_as_float((A[s].y<<16)|(B[s].y&0xffffu));
      hL[par][(m0+2)&7][i32 + ((m0+2)>>3)] = __uint_as_float((A[s].z<<16)|(B[s].z&0xffffu));
      hL[par][(m0+3)&7][i32 + ((m0+3)>>3)] = __uint_as_float((A[s].w<<16)|(B[s].w&0xffffu));
    }
    __syncthreads();

    // ---- recurrent dot from LDS ----
    const float* hrow = hL[par][bl];
    float a0=0.f,a1=0.f,a2=0.f,a3=0.f;
    for (int k = 0; k < NHID; k += 4) {
      const float4 wv = *(const float4*)&Ws[jl][k];
      const float4 hv = *(const float4*)&hrow[k];
      a0 = fmaf(wv.x, hv.x, a0); a1 = fmaf(wv.y, hv.y, a1);
      a2 = fmaf(wv.z, hv.z, a2); a3 = fmaf(wv.w, hv.w, a3);
    }
    const float hnew = tanhf(accx + (a0+a1)+(a2+a3));

    // ---- publish h(t+1): two tagged halves, fire-and-forget ----
    {
      const u32 bits = __float_as_uint(hnew);
      const u32 tag  = (u32)(t+1) << 16;
      u32* dst = hw + ((t+1)&1)*WORDS_PER_PAR + ((gj*GB + gb) << 9);
      const int m = (jl << 3) + bl;           // == tid, unit-stride stores
      st_coh4(dst + m,       tag | (bits >> 16));
      st_coh4(dst + 256 + m, tag | (bits & 0xffffu));
    }

    // ---- x-projection for t+1 (overlaps peers' publish flight) ----
    if (t + 1 < SEQ) {
      const float* xr = x + ((size_t)(t+1)*BATCH + b)*NIN;
      float c0=0.f,c1=0.f,c2=0.f,c3=0.f;
      for (int k = 0; k < NIN; k += 4) {
        const float4 wv = *(const float4*)&Wi[jl][k];
        const float4 xv = *(const float4*)&xr[k];
        c0 = fmaf(wv.x, xv.x, c0); c1 = fmaf(wv.y, xv.y, c1);
        c2 = fmaf(wv.z, xv.z, c2); c3 = fmaf(wv.w, xv.w, c3);
      }
      accx = (c0+c1)+(c2+c3) + bias;
    }
  }
}

// h_final = h(2048) lives in parity 0 (2048 even), wire format
__global__ __launch_bounds__(NOUT, 1)
void rnn_out_kernel(const u32* __restrict__ hw,
                    const float* __restrict__ Who,
                    const float* __restrict__ bho,
                    float* __restrict__ out)
{
  const int b = blockIdx.x;    // 64
  const int o = threadIdx.x;   // 128
  __shared__ float hB[NHID];
  for (int k = o; k < NHID; k += NOUT) {
    const int slice = (k >> 5)*GB + (b >> 3);
    const int m     = ((k & 31) << 3) + (b & 7);
    const u32 hi = hw[(slice << 9) + m];
    const u32 lo = hw[(slice << 9) + 256 + m];
    hB[k] = __uint_as_float((hi << 16) | (lo & 0xffffu));
  }
  __syncthreads();
  const float* wr = Who + (size_t)o*NHID;
  float a0=0.f,a1=0.f,a2=0.f,a3=0.f;
  for (int k = 0; k < NHID; k += 4) {
    const float4 wv = *(const float4*)&wr[k];
    a0 = fmaf(wv.x, hB[k  ], a0);
    a1 = fmaf(wv.y, hB[k+1], a1);
    a2 = fmaf(wv.z, hB[k+2], a2);
    a3 = fmaf(wv.w, hB[k+3], a3);
  }
  out[(size_t)b*NOUT + o] = (a0+a1)+(a2+a3) + bho[o];
}

extern "C" void kernel_launch(void* const* d_in, const int* in_sizes, int n_in,
                              void* d_out, int out_size, void* d_ws, size_t ws_size,
                              hipStream_t stream)
{
  const float* x   = (const float*)d_in[0];
  const float* Wih = (const float*)d_in[1];
  const float* bih = (const float*)d_in[2];
  const float* Whh = (const float*)d_in[3];
  const float* bhh = (const float*)d_in[4];
  const float* Who = (const float*)d_in[5];
  const float* bho = (const float*)d_in[6];
  float* out = (float*)d_out;
  u32*   hw  = (u32*)d_ws;

  // zero wire buffer: tag0/value0 == h(0)=0; deterministic graph replay
  hipMemsetAsync(d_ws, 0, (size_t)HBUF_WORDS*sizeof(u32), stream);

  rnn_persist_kernel<<<dim3(GB*GJ), dim3(256), 0, stream>>>(x, Wih, bih, Whh, bhh, hw);
  rnn_out_kernel<<<dim3(BATCH), dim3(NOUT), 0, stream>>>(hw, Who, bho, out);
}

// Round 5
// 15452.531 us; speedup vs baseline: 3.9578x; 1.5145x over previous
//
#include <hip/hip_runtime.h>
#include <math.h>

#define SEQ   2048
#define BATCH 64
#define NIN   256
#define NHID  512
#define NOUT  128

#define GB 8                    // batch groups (8 batch rows each)
#define GJ 16                   // hidden groups (32 j each)
#define BPG (BATCH/GB)          // 8
#define JPG (NHID/GJ)           // 32

// LDS pads: stride%32==4 -> banks spread, 16B-aligned rows
#define WS_PAD 516
#define WI_PAD 260
#define HL_PAD 516
#define XL_PAD 260

// h wire format: float -> pair of u32 words (tag<<16|hi16, tag<<16|lo16),
// interleaved per slice: word[2m]=hi(m), word[2m+1]=lo(m), m=jl*8+bl.
// Words are individually self-validating => no fences at any scope.
// ALL wire traffic is system-scope (sc0 sc1): IC-coherent, L1/L2-bypassing.
// (Round-4 lesson: sc0-only polls spin on stale L1 lines forever -> hang.)
#define WORDS_PER_SLICE 512
#define WORDS_PER_PAR   (GJ*GB*WORDS_PER_SLICE)   // 65536
#define HBUF_WORDS      (2*WORDS_PER_PAR)          // 131072 (512 KB)

typedef unsigned int u32;
typedef u32 u32x2 __attribute__((ext_vector_type(2)));
typedef u32 u32x4 __attribute__((ext_vector_type(4)));

__device__ __forceinline__ u32x4 ld16_ic(const u32* p) {
  u32x4 r;
  asm volatile("global_load_dwordx4 %0, %1, off sc0 sc1"
               : "=v"(r) : "v"(p) : "memory");
  return r;
}
__device__ __forceinline__ void st8_ic(u32* p, u32x2 v) {
  asm volatile("global_store_dwordx2 %0, %1, off sc0 sc1"
               :: "v"(p), "v"(v) : "memory");
}
__device__ __forceinline__ void wait_vm0() {
  asm volatile("s_waitcnt vmcnt(0)" ::: "memory");
  __builtin_amdgcn_sched_barrier(0);   // keep uses after the wait (rule #18)
}
// fire-and-forget global->LDS, 16B/lane; LDS base must be wave-uniform
__device__ __forceinline__ void gload_lds16(const float* g, float* l) {
  __builtin_amdgcn_global_load_lds(
      (const __attribute__((address_space(1))) float*)g,
      (__attribute__((address_space(3))) float*)l, 16, 0, 0);
}
__device__ __forceinline__ int tags8_ok(u32x4 a, u32x4 b, u32 t) {
  return (a.x>>16)==t && (a.y>>16)==t && (a.z>>16)==t && (a.w>>16)==t &&
         (b.x>>16)==t && (b.y>>16)==t && (b.z>>16)==t && (b.w>>16)==t;
}

// ILP-batched dot: 8 loads in flight, 16 FMAs per body; accumulator a_i
// takes k%4==i terms -> bitwise-identical to the proven k+=4 ordering.
__device__ __forceinline__ float dot16(const float* __restrict__ wr,
                                       const float* __restrict__ hr, int n) {
  float a0=0.f,a1=0.f,a2=0.f,a3=0.f;
  #pragma unroll 2
  for (int k = 0; k < n; k += 16) {
    const float4 w0 = *(const float4*)(wr+k);
    const float4 w1 = *(const float4*)(wr+k+4);
    const float4 w2 = *(const float4*)(wr+k+8);
    const float4 w3 = *(const float4*)(wr+k+12);
    const float4 h0 = *(const float4*)(hr+k);
    const float4 h1 = *(const float4*)(hr+k+4);
    const float4 h2 = *(const float4*)(hr+k+8);
    const float4 h3 = *(const float4*)(hr+k+12);
    a0=fmaf(w0.x,h0.x,a0); a1=fmaf(w0.y,h0.y,a1); a2=fmaf(w0.z,h0.z,a2); a3=fmaf(w0.w,h0.w,a3);
    a0=fmaf(w1.x,h1.x,a0); a1=fmaf(w1.y,h1.y,a1); a2=fmaf(w1.z,h1.z,a2); a3=fmaf(w1.w,h1.w,a3);
    a0=fmaf(w2.x,h2.x,a0); a1=fmaf(w2.y,h2.y,a1); a2=fmaf(w2.z,h2.z,a2); a3=fmaf(w2.w,h2.w,a3);
    a0=fmaf(w3.x,h3.x,a0); a1=fmaf(w3.y,h3.y,a1); a2=fmaf(w3.z,h3.z,a2); a3=fmaf(w3.w,h3.w,a3);
  }
  return (a0+a1)+(a2+a3);
}

__global__ __launch_bounds__(256, 1)
void rnn_persist_kernel(const float* __restrict__ x,
                        const float* __restrict__ Wih,
                        const float* __restrict__ bih,
                        const float* __restrict__ Whh,
                        const float* __restrict__ bhh,
                        u32* __restrict__ hw)
{
  const int gj  = blockIdx.x >> 3;   // 0..15
  const int gb  = blockIdx.x & 7;    // 0..7
  const int tid = threadIdx.x;
  const int jl  = tid >> 3;          // 0..31
  const int bl  = tid & 7;           // 0..7
  const int b   = gb*BPG + bl;
  const int w   = tid >> 6;          // wave 0..3
  const int lane= tid & 63;

  __shared__ __align__(16) float Ws[JPG][WS_PAD];    // 66.0 KB
  __shared__ __align__(16) float Wi[JPG][WI_PAD];    // 33.3 KB
  __shared__ __align__(16) float hL[2][BPG][HL_PAD]; // 33.0 KB
  __shared__ __align__(16) float xL[3][BPG][XL_PAD]; // 25.0 KB  (157.3 total)

  for (int idx = tid; idx < JPG*NHID; idx += 256) {
    const int jj = idx >> 9, kk = idx & (NHID-1);
    Ws[jj][kk] = Whh[(size_t)(gj*JPG+jj)*NHID + kk];
  }
  for (int idx = tid; idx < JPG*NIN; idx += 256) {
    const int jj = idx >> 8, kk = idx & (NIN-1);
    Wi[jj][kk] = Wih[(size_t)(gj*JPG+jj)*NIN + kk];
  }
  const float bias = bih[gj*JPG+jl] + bhh[gj*JPG+jl];
  __syncthreads();

  // prologue: prefetch x(1) -> slab 1 (wave w stages batch rows 2w,2w+1)
  {
    const float* s0 = x + ((size_t)1*BATCH + gb*BPG + (w<<1))*NIN + (lane<<2);
    gload_lds16(s0,       &xL[1][(w<<1)  ][0]);
    gload_lds16(s0 + NIN, &xL[1][(w<<1)+1][0]);
  }
  // prologue: issue polls for t=0 (memset tag0|0 == h(0)=0 -> instant hit)
  u32x4 A[4], B[4];
  const u32* pp[4];
  #pragma unroll
  for (int s = 0; s < 4; ++s) {
    pp[s] = hw + ((((w<<2)+s)*GB + gb) << 9) + (lane<<3);
    A[s] = ld16_ic(pp[s]);
    B[s] = ld16_ic(pp[s] + 4);
  }
  // x(0)-projection straight from global (once)
  float accx = dot16(&Wi[jl][0], x + (size_t)b*NIN, NIN) + bias;

  for (int t = 0; t < SEQ; ++t) {
    const int par = t & 1;
    const u32 tg  = (u32)t;

    // ---- check + stage h(t); concurrent re-poll of stale slices ----
    wait_vm0();
    u32 pend = 0xFu;
    int guard = 1 << 16;           // watchdog: bug => fast absmax-fail, not hang
    do {
      u32 nxt = 0;
      #pragma unroll
      for (int s = 0; s < 4; ++s) if (pend & (1u<<s)) {
        if (__all(tags8_ok(A[s], B[s], tg))) {
          const int m0 = lane << 2;                // float index 4*lane
          const int c0 = ((w<<2)+s) << 5;          // column base = slice*32
          hL[par][(m0  )&7][c0 + ((m0  )>>3)] = __uint_as_float((A[s].x<<16)|(A[s].y&0xffffu));
          hL[par][(m0+1)&7][c0 + ((m0+1)>>3)] = __uint_as_float((A[s].z<<16)|(A[s].w&0xffffu));
          hL[par][(m0+2)&7][c0 + ((m0+2)>>3)] = __uint_as_float((B[s].x<<16)|(B[s].y&0xffffu));
          hL[par][(m0+3)&7][c0 + ((m0+3)>>3)] = __uint_as_float((B[s].z<<16)|(B[s].w&0xffffu));
        } else nxt |= 1u<<s;
      }
      if (nxt) {
        #pragma unroll
        for (int s = 0; s < 4; ++s) if (nxt & (1u<<s)) {
          A[s] = ld16_ic(pp[s]);
          B[s] = ld16_ic(pp[s] + 4);
        }
        wait_vm0();
      }
      pend = (--guard == 0) ? 0u : nxt;
    } while (pend);

    __syncthreads();   // implicit vmcnt(0) is cheap here (nothing in flight)

    // prefetch x(t+2) AFTER the barrier: drains at t+1's poll wait, a full
    // compute-phase away; consumers read it after t+1's barrier.
    if (t + 2 < SEQ) {
      const int sl = (t+2)%3;
      const float* s0 = x + ((size_t)(t+2)*BATCH + gb*BPG + (w<<1))*NIN + (lane<<2);
      gload_lds16(s0,       &xL[sl][(w<<1)  ][0]);
      gload_lds16(s0 + NIN, &xL[sl][(w<<1)+1][0]);
    }

    // ---- recurrent dot + activation ----
    const float hnew = tanhf(accx + dot16(&Ws[jl][0], &hL[par][bl][0], NHID));

    // ---- publish h(t+1): one 8B store of two tagged halves ----
    {
      const u32 bits = __float_as_uint(hnew);
      const u32 tag  = (u32)(t+1) << 16;
      u32x2 pv; pv.x = tag | (bits >> 16); pv.y = tag | (bits & 0xffffu);
      st8_ic(hw + ((t+1)&1)*WORDS_PER_PAR + ((gj*GB+gb)<<9) + (tid<<1), pv);
    }

    if (t + 1 < SEQ) {
      // issue polls for t+1 now; detect latency overlaps the x-projection
      const u32* nb = hw + ((t+1)&1)*WORDS_PER_PAR;
      #pragma unroll
      for (int s = 0; s < 4; ++s) {
        pp[s] = nb + ((((w<<2)+s)*GB + gb) << 9) + (lane<<3);
        A[s] = ld16_ic(pp[s]);
        B[s] = ld16_ic(pp[s] + 4);
      }
      // x-projection for t+1 from the prefetched LDS slab
      accx = dot16(&Wi[jl][0], &xL[(t+1)%3][bl][0], NIN) + bias;
    }
  }
}

// h_final = h(2048), parity 0, wire format
__global__ __launch_bounds__(NOUT, 1)
void rnn_out_kernel(const u32* __restrict__ hw,
                    const float* __restrict__ Who,
                    const float* __restrict__ bho,
                    float* __restrict__ out)
{
  const int b = blockIdx.x;    // 64
  const int o = threadIdx.x;   // 128
  __shared__ __align__(16) float hB[NHID];
  for (int k = o; k < NHID; k += NOUT) {
    const int slice = (k >> 5)*GB + (b >> 3);
    const int m     = ((k & 31) << 3) + (b & 7);
    const u32 hi = hw[(slice << 9) + (m << 1)];
    const u32 lo = hw[(slice << 9) + (m << 1) + 1];
    hB[k] = __uint_as_float((hi << 16) | (lo & 0xffffu));
  }
  __syncthreads();
  out[(size_t)b*NOUT + o] = dot16(Who + (size_t)o*NHID, hB, NHID) + bho[o];
}

extern "C" void kernel_launch(void* const* d_in, const int* in_sizes, int n_in,
                              void* d_out, int out_size, void* d_ws, size_t ws_size,
                              hipStream_t stream)
{
  const float* x   = (const float*)d_in[0];
  const float* Wih = (const float*)d_in[1];
  const float* bih = (const float*)d_in[2];
  const float* Whh = (const float*)d_in[3];
  const float* bhh = (const float*)d_in[4];
  const float* Who = (const float*)d_in[5];
  const float* bho = (const float*)d_in[6];
  float* out = (float*)d_out;
  u32*   hw  = (u32*)d_ws;

  // zero wire buffer (tag0|0 == h(0)=0); deterministic graph replay
  hipMemsetAsync(d_ws, 0, (size_t)HBUF_WORDS*sizeof(u32), stream);

  rnn_persist_kernel<<<dim3(GB*GJ), dim3(256), 0, stream>>>(x, Wih, bih, Whh, bhh, hw);
  rnn_out_kernel<<<dim3(BATCH), dim3(NOUT), 0, stream>>>(hw, Who, bho, out);
}

// Round 6
// 14223.378 us; speedup vs baseline: 4.2998x; 1.0864x over previous
//
#include <hip/hip_runtime.h>
#include <math.h>

#define SEQ   2048
#define BATCH 64
#define NIN   256
#define NHID  512
#define NOUT  128

#define GB 8                    // batch groups (8 batch rows each)
#define GJ 16                   // hidden groups (32 j each)

// transposed LDS tiles; stride 132 (132%32==4) spreads banks, 16B-aligned
#define HT_ST 132
#define XT_ST 132

// h wire format: float -> pair of u32 (tag<<16|hi16, tag<<16|lo16), words
// [2m],[2m+1] of the slice, m = j*8+b. Self-validating => no fences.
// All wire traffic system-scope (sc0 sc1). (r4 lesson: sc0-only hangs.)
#define WORDS_PER_SLICE 512
#define WORDS_PER_PAR   (GJ*GB*WORDS_PER_SLICE)   // 65536
#define HBUF_WORDS      (2*WORDS_PER_PAR)          // 512 KB

typedef unsigned int u32;
typedef u32 u32x2 __attribute__((ext_vector_type(2)));
typedef u32 u32x4 __attribute__((ext_vector_type(4)));

__device__ __forceinline__ u32x4 ld16_ic(const u32* p) {
  u32x4 r;
  asm volatile("global_load_dwordx4 %0, %1, off sc0 sc1"
               : "=v"(r) : "v"(p) : "memory");
  return r;
}
__device__ __forceinline__ void st8_ic(u32* p, u32x2 v) {
  asm volatile("global_store_dwordx2 %0, %1, off sc0 sc1"
               :: "v"(p), "v"(v) : "memory");
}
__device__ __forceinline__ void wait_vm0() {
  asm volatile("s_waitcnt vmcnt(0)" ::: "memory");
  __builtin_amdgcn_sched_barrier(0);
}
__device__ __forceinline__ int tags8_ok(u32x4 a, u32x4 b, u32 t) {
  return (a.x>>16)==t && (a.y>>16)==t && (a.z>>16)==t && (a.w>>16)==t &&
         (b.x>>16)==t && (b.y>>16)==t && (b.z>>16)==t && (b.w>>16)==t;
}

// acc[jj*4+bb] += W[jj] * H[bb]
#define FMA16(W, H) do { \
  a[0] =fmaf((W).x,(H).x,a[0]);  a[1] =fmaf((W).x,(H).y,a[1]);  \
  a[2] =fmaf((W).x,(H).z,a[2]);  a[3] =fmaf((W).x,(H).w,a[3]);  \
  a[4] =fmaf((W).y,(H).x,a[4]);  a[5] =fmaf((W).y,(H).y,a[5]);  \
  a[6] =fmaf((W).y,(H).z,a[6]);  a[7] =fmaf((W).y,(H).w,a[7]);  \
  a[8] =fmaf((W).z,(H).x,a[8]);  a[9] =fmaf((W).z,(H).y,a[9]);  \
  a[10]=fmaf((W).z,(H).z,a[10]); a[11]=fmaf((W).z,(H).w,a[11]); \
  a[12]=fmaf((W).w,(H).x,a[12]); a[13]=fmaf((W).w,(H).y,a[13]); \
  a[14]=fmaf((W).w,(H).z,a[14]); a[15]=fmaf((W).w,(H).w,a[15]); \
} while (0)

// x(T) block slice load: thread covers float4 #f of its 2 (idx = tid*2+f)
#define XLOAD(T, f) \
  (*(const float4*)(x + ((size_t)(T)*BATCH + gb*8 + ((tid*2+(f))>>6))*NIN + \
                    (((tid*2+(f))&63)<<2)))

__global__ __launch_bounds__(256, 1)
void rnn_persist_kernel(const float* __restrict__ x,
                        const float* __restrict__ Wih,
                        const float* __restrict__ bih,
                        const float* __restrict__ Whh,
                        const float* __restrict__ bhh,
                        u32* __restrict__ hw)
{
  const int gj  = blockIdx.x >> 3;   // 0..15 hidden group
  const int gb  = blockIdx.x & 7;    // 0..7  batch group
  const int tid = threadIdx.x;
  const int jt  = tid >> 5;          // 0..7  j-tile (4 j's)
  const int bt  = (tid >> 4) & 1;    // 0..1  b-tile (4 b's)
  const int ks  = tid & 15;          // 0..15 k-split slot
  const int w   = tid >> 6, lane = tid & 63;

  __shared__ __align__(16) float hT[2][32][HT_ST];  // [par][k'][ks*8+b] 33.8KB
  __shared__ __align__(16) float xT[2][16][XT_ST];  // [par][k'][ks*8+b] 16.9KB

  // ---- register-resident weight tiles (one-time global loads) ----
  float4 Wr[32], Wx[16];
  const int j0 = gj*32 + jt*4;
  #pragma unroll
  for (int kk = 0; kk < 32; ++kk) {
    const int k = (ks << 5) + kk;
    Wr[kk].x = Whh[(size_t)(j0+0)*NHID + k];
    Wr[kk].y = Whh[(size_t)(j0+1)*NHID + k];
    Wr[kk].z = Whh[(size_t)(j0+2)*NHID + k];
    Wr[kk].w = Whh[(size_t)(j0+3)*NHID + k];
  }
  #pragma unroll
  for (int kk = 0; kk < 16; ++kk) {
    const int k = (ks << 4) + kk;
    Wx[kk].x = Wih[(size_t)(j0+0)*NIN + k];
    Wx[kk].y = Wih[(size_t)(j0+1)*NIN + k];
    Wx[kk].z = Wih[(size_t)(j0+2)*NIN + k];
    Wx[kk].w = Wih[(size_t)(j0+3)*NIN + k];
  }
  const int jo = jt*4 + (ks >> 2);     // this lane's final output j (in block)
  const int bo = bt*4 + (ks & 3);      // and b (in group)
  const float bias  = bih[gj*32 + jo] + bhh[gj*32 + jo];
  const int   hslot = (ks << 3) + (bt << 2);   // word offset in hT/xT rows

  // ---- prologue: x(0) -> xT[0]; x(1) -> regs; polls for t=0 ----
  float4 x0a = XLOAD(0,0), x0b = XLOAD(0,1);
  float4 xB0 = XLOAD(1,0), xB1 = XLOAD(1,1);
  {
    const int c = ((tid*2)&63) << 2;      // x(0) slot f=0
    const int kp = c & 15, sl = ((c>>4)<<3) + ((tid*2)>>6);
    xT[0][kp+0][sl]=x0a.x; xT[0][kp+1][sl]=x0a.y; xT[0][kp+2][sl]=x0a.z; xT[0][kp+3][sl]=x0a.w;
    const int c1 = ((tid*2+1)&63) << 2;   // f=1
    const int kp1 = c1 & 15, sl1 = ((c1>>4)<<3) + ((tid*2+1)>>6);
    xT[0][kp1+0][sl1]=x0b.x; xT[0][kp1+1][sl1]=x0b.y; xT[0][kp1+2][sl1]=x0b.z; xT[0][kp1+3][sl1]=x0b.w;
  }
  u32x4 A[4], B[4];
  const u32* pp[4];
  #pragma unroll
  for (int s = 0; s < 4; ++s) {
    pp[s] = hw + ((((w<<2)+s)*GB + gb) << 9) + (lane<<3);
    A[s] = ld16_ic(pp[s]);  B[s] = ld16_ic(pp[s] + 4);
  }

  for (int t = 0; t < SEQ; ++t) {
    const int par = t & 1, par2 = par ^ 1;
    const u32 tg = (u32)t;

    // ---- check + stage h(t) -> hT[par]; concurrent re-poll ----
    wait_vm0();
    u32 pend = 0xFu;
    int guard = 1 << 16;          // watchdog: bug => absmax-fail, not hang
    do {
      u32 nxt = 0;
      #pragma unroll
      for (int s = 0; s < 4; ++s) if (pend & (1u<<s)) {
        if (__all(tags8_ok(A[s], B[s], tg))) {
          const int i = (w<<2) + s;                 // source slice = ks-slot
          const int krow = lane >> 1;               // k' row
          const int cb = (i<<3) + ((lane&1)<<2);    // 4-aligned col
          float4 hv;
          hv.x = __uint_as_float((A[s].x<<16)|(A[s].y&0xffffu));
          hv.y = __uint_as_float((A[s].z<<16)|(A[s].w&0xffffu));
          hv.z = __uint_as_float((B[s].x<<16)|(B[s].y&0xffffu));
          hv.w = __uint_as_float((B[s].z<<16)|(B[s].w&0xffffu));
          *(float4*)&hT[par][krow][cb] = hv;
        } else nxt |= 1u<<s;
      }
      if (nxt) {
        #pragma unroll
        for (int s = 0; s < 4; ++s) if (nxt & (1u<<s)) {
          A[s] = ld16_ic(pp[s]);  B[s] = ld16_ic(pp[s] + 4);
        }
        wait_vm0();
      }
      pend = (--guard == 0) ? 0u : nxt;
    } while (pend);
    __syncthreads();

    // ---- xT[par2] <- x(t+1) regs (post-barrier write, race-free) ----
    if (t + 1 < SEQ) {
      const int c = ((tid*2)&63) << 2;
      const int kp = c & 15, sl = ((c>>4)<<3) + ((tid*2)>>6);
      xT[par2][kp+0][sl]=xB0.x; xT[par2][kp+1][sl]=xB0.y;
      xT[par2][kp+2][sl]=xB0.z; xT[par2][kp+3][sl]=xB0.w;
      const int c1 = ((tid*2+1)&63) << 2;
      const int kp1 = c1 & 15, sl1 = ((c1>>4)<<3) + ((tid*2+1)>>6);
      xT[par2][kp1+0][sl1]=xB1.x; xT[par2][kp1+1][sl1]=xB1.y;
      xT[par2][kp1+2][sl1]=xB1.z; xT[par2][kp1+3][sl1]=xB1.w;
    }
    if (t + 2 < SEQ) { xB0 = XLOAD(t+2,0); xB1 = XLOAD(t+2,1); }

    // ---- compute 4x4 partial tile: 48 b128 reads, 768 FMAs ----
    float a[16];
    #pragma unroll
    for (int i = 0; i < 16; ++i) a[i] = 0.f;
    #pragma unroll
    for (int kk = 0; kk < 32; ++kk) {
      const float4 hv = *(const float4*)&hT[par][kk][hslot];
      FMA16(Wr[kk], hv);
    }
    #pragma unroll
    for (int kk = 0; kk < 16; ++kk) {
      const float4 xv = *(const float4*)&xT[par][kk][hslot];
      FMA16(Wx[kk], xv);
    }

    // ---- butterfly k-reduction over the 16 ks-lanes (width 16) ----
    #pragma unroll
    for (int bb = 0; bb < 4; ++bb) {
      const int d = 1 << bb, n = 16 >> bb;
      const bool hi = (ks >> bb) & 1;
      float tt[16];
      #pragma unroll
      for (int i = 0; i < n; ++i) tt[i] = __shfl_xor(a[i], d, 16);
      #pragma unroll
      for (int i = 0; i < n/2; ++i)
        a[i] = hi ? (a[2*i+1] + tt[2*i+1]) : (a[2*i] + tt[2*i]);
    }
    // lane owns output (jo, bo)
    const float hnew = tanhf(a[0] + bias);

    // ---- publish h(t+1) ----
    {
      const u32 bits = __float_as_uint(hnew);
      const u32 tag  = (u32)(t+1) << 16;
      u32x2 pv; pv.x = tag | (bits >> 16); pv.y = tag | (bits & 0xffffu);
      const int m = jo*8 + bo;
      st8_ic(hw + par2*WORDS_PER_PAR + ((gj*GB+gb)<<9) + (m<<1), pv);
    }

    // ---- issue polls for t+1 (overlap with peers' publish flight) ----
    if (t + 1 < SEQ) {
      const u32* nb = hw + par2*WORDS_PER_PAR;
      #pragma unroll
      for (int s = 0; s < 4; ++s) {
        pp[s] = nb + ((((w<<2)+s)*GB + gb) << 9) + (lane<<3);
        A[s] = ld16_ic(pp[s]);  B[s] = ld16_ic(pp[s] + 4);
      }
    }
  }
}

// h_final = h(2048), parity 0, wire format
__global__ __launch_bounds__(NOUT, 1)
void rnn_out_kernel(const u32* __restrict__ hw,
                    const float* __restrict__ Who,
                    const float* __restrict__ bho,
                    float* __restrict__ out)
{
  const int b = blockIdx.x;    // 64
  const int o = threadIdx.x;   // 128
  __shared__ __align__(16) float hB[NHID];
  for (int k = o; k < NHID; k += NOUT) {
    const int slice = (k >> 5)*GB + (b >> 3);
    const int m     = ((k & 31) << 3) + (b & 7);
    const u32 hi = hw[(slice << 9) + (m << 1)];
    const u32 lo = hw[(slice << 9) + (m << 1) + 1];
    hB[k] = __uint_as_float((hi << 16) | (lo & 0xffffu));
  }
  __syncthreads();
  const float* wr = Who + (size_t)o*NHID;
  float a0=0.f,a1=0.f,a2=0.f,a3=0.f;
  for (int k = 0; k < NHID; k += 4) {
    const float4 wv = *(const float4*)&wr[k];
    a0 = fmaf(wv.x, hB[k  ], a0);
    a1 = fmaf(wv.y, hB[k+1], a1);
    a2 = fmaf(wv.z, hB[k+2], a2);
    a3 = fmaf(wv.w, hB[k+3], a3);
  }
  out[(size_t)b*NOUT + o] = (a0+a1)+(a2+a3) + bho[o];
}

extern "C" void kernel_launch(void* const* d_in, const int* in_sizes, int n_in,
                              void* d_out, int out_size, void* d_ws, size_t ws_size,
                              hipStream_t stream)
{
  const float* x   = (const float*)d_in[0];
  const float* Wih = (const float*)d_in[1];
  const float* bih = (const float*)d_in[2];
  const float* Whh = (const float*)d_in[3];
  const float* bhh = (const float*)d_in[4];
  const float* Who = (const float*)d_in[5];
  const float* bho = (const float*)d_in[6];
  float* out = (float*)d_out;
  u32*   hw  = (u32*)d_ws;

  // zero wire buffer (tag0|0 == h(0)=0); deterministic graph replay
  hipMemsetAsync(d_ws, 0, (size_t)HBUF_WORDS*sizeof(u32), stream);

  rnn_persist_kernel<<<dim3(GB*GJ), dim3(256), 0, stream>>>(x, Wih, bih, Whh, bhh, hw);
  rnn_out_kernel<<<dim3(BATCH), dim3(NOUT), 0, stream>>>(hw, Who, bho, out);
}

// Round 7
// 9085.821 us; speedup vs baseline: 6.7312x; 1.5654x over previous
//
#include <hip/hip_runtime.h>
#include <math.h>

#define SEQ   2048
#define BATCH 64
#define NIN   256
#define NHID  512
#define NOUT  128

#define GB 8                    // batch groups (8 batch rows each)
#define GJ 16                   // hidden groups (32 j each)

// h wire format: float -> pair of u32 (tag<<16|hi16, tag<<16|lo16), words
// [2m],[2m+1] of the slice, m = j*8+b. Self-validating => no fences.
// All wire traffic system-scope (sc0 sc1). (r4 lesson: sc0-only hangs.)
#define WORDS_PER_SLICE 512
#define WORDS_PER_PAR   (GJ*GB*WORDS_PER_SLICE)   // 65536
#define HBUF_WORDS      (2*WORDS_PER_PAR)          // 512 KB
#define WIRE_BYTES      ((size_t)HBUF_WORDS*4)
#define XP_BYTES        ((size_t)SEQ*BATCH*NHID*4) // 268.4 MB precomputed x-proj

typedef unsigned int u32;
typedef u32 u32x2 __attribute__((ext_vector_type(2)));
typedef u32 u32x4 __attribute__((ext_vector_type(4)));

__device__ __forceinline__ u32x4 ld16_ic(const u32* p) {
  u32x4 r;
  asm volatile("global_load_dwordx4 %0, %1, off sc0 sc1"
               : "=v"(r) : "v"(p) : "memory");
  return r;
}
__device__ __forceinline__ void st8_ic(u32* p, u32x2 v) {
  asm volatile("global_store_dwordx2 %0, %1, off sc0 sc1"
               :: "v"(p), "v"(v) : "memory");
}
__device__ __forceinline__ void wait_vm0() {
  asm volatile("s_waitcnt vmcnt(0)" ::: "memory");
  __builtin_amdgcn_sched_barrier(0);   // keep uses after the wait (rule #18)
}
__device__ __forceinline__ int tags8_ok(u32x4 a, u32x4 b, u32 t) {
  return (a.x>>16)==t && (a.y>>16)==t && (a.z>>16)==t && (a.w>>16)==t &&
         (b.x>>16)==t && (b.y>>16)==t && (b.z>>16)==t && (b.w>>16)==t;
}

// additive swizzle on 4-aligned LDS column bases: spreads the stride-8
// hslot pattern from 4-way to 2-way (free) bank aliasing. max col 136 -> 140.
__device__ __forceinline__ int swz(int c) { return c + ((c >> 5) << 2); }
#define HT_ST 140

// acc[jj*4+bb] += W[jj] * H[bb]
#define FMA16(W, H) do { \
  a[0] =fmaf((W).x,(H).x,a[0]);  a[1] =fmaf((W).x,(H).y,a[1]);  \
  a[2] =fmaf((W).x,(H).z,a[2]);  a[3] =fmaf((W).x,(H).w,a[3]);  \
  a[4] =fmaf((W).y,(H).x,a[4]);  a[5] =fmaf((W).y,(H).y,a[5]);  \
  a[6] =fmaf((W).y,(H).z,a[6]);  a[7] =fmaf((W).y,(H).w,a[7]);  \
  a[8] =fmaf((W).z,(H).x,a[8]);  a[9] =fmaf((W).z,(H).y,a[9]);  \
  a[10]=fmaf((W).z,(H).z,a[10]); a[11]=fmaf((W).z,(H).w,a[11]); \
  a[12]=fmaf((W).w,(H).x,a[12]); a[13]=fmaf((W).w,(H).y,a[13]); \
  a[14]=fmaf((W).w,(H).z,a[14]); a[15]=fmaf((W).w,(H).w,a[15]); \
} while (0)

#define XLOAD(T, f) \
  (*(const float4*)(x + ((size_t)(T)*BATCH + gb*8 + ((tid*2+(f))>>6))*NIN + \
                    (((tid*2+(f))&63)<<2)))

// ---------------- x-projection precompute GEMM (MODE 0 path) ----------------
// xp[row][j] = x[row,:]·Wih[j,:] + bih[j] + bhh[j];  row = t*64+b (x layout).
// 2048 blocks = 256 m-groups x 8 j-tiles; each block: W^T staged once,
// then 8 m-tiles of 64 rows. All LDS patterns <=2-way bank aliasing.
__global__ __launch_bounds__(256, 1)
void xproj_kernel(const float* __restrict__ x,
                  const float* __restrict__ Wih,
                  const float* __restrict__ bih,
                  const float* __restrict__ bhh,
                  float* __restrict__ xp)
{
  const int bj = blockIdx.x & 7;        // j-tile (64 j)
  const int bm = blockIdx.x >> 3;       // m-group (512 rows)
  const int tid = threadIdx.x;
  const int tx = tid & 15, ty = tid >> 4;

  __shared__ __align__(16) float  wT[NIN][68];   // [k][j] transposed, 69.6 KB
  __shared__ __align__(16) float4 xS[64][66];    // [m][kq] k-vectorized, 67.6 KB

  // stage W^T: lane owns row j=tid&63, walks k in 64B-line-friendly steps.
  // LDS writes are j-contiguous per wave -> conflict-free.
  for (int it = 0; it < 64; ++it) {
    const int widx = tid + (it << 8);
    const int k = widx >> 6, j = widx & 63;
    wT[k][j] = Wih[(size_t)(bj*64 + j)*NIN + k];
  }
  const int jg = bj*64 + tx*4;
  float4 bv;
  bv.x = bih[jg+0]+bhh[jg+0]; bv.y = bih[jg+1]+bhh[jg+1];
  bv.z = bih[jg+2]+bhh[jg+2]; bv.w = bih[jg+3]+bhh[jg+3];
  __syncthreads();

  for (int mt = 0; mt < 8; ++mt) {
    const size_t r0 = (size_t)bm*512 + mt*64;
    // stage 64 x-rows as float4 (coalesced global, 2-way LDS writes)
    for (int it = 0; it < 16; ++it) {
      const int f = tid + (it << 8);
      const int m = f >> 6, kq = f & 63;
      xS[m][kq] = *(const float4*)&x[(r0 + m)*NIN + (kq << 2)];
    }
    __syncthreads();

    float acc[4][4];
    #pragma unroll
    for (int q = 0; q < 4; ++q)
      #pragma unroll
      for (int jj = 0; jj < 4; ++jj) acc[q][jj] = 0.f;

    for (int kq = 0; kq < 64; ++kq) {
      const float4 xv0 = xS[ty*4+0][kq];
      const float4 xv1 = xS[ty*4+1][kq];
      const float4 xv2 = xS[ty*4+2][kq];
      const float4 xv3 = xS[ty*4+3][kq];
      #pragma unroll
      for (int i = 0; i < 4; ++i) {
        const float4 wv = *(const float4*)&wT[(kq<<2)+i][tx*4];
        const float xi0 = (i==0)?xv0.x:(i==1)?xv0.y:(i==2)?xv0.z:xv0.w;
        const float xi1 = (i==0)?xv1.x:(i==1)?xv1.y:(i==2)?xv1.z:xv1.w;
        const float xi2 = (i==0)?xv2.x:(i==1)?xv2.y:(i==2)?xv2.z:xv2.w;
        const float xi3 = (i==0)?xv3.x:(i==1)?xv3.y:(i==2)?xv3.z:xv3.w;
        acc[0][0]=fmaf(xi0,wv.x,acc[0][0]); acc[0][1]=fmaf(xi0,wv.y,acc[0][1]);
        acc[0][2]=fmaf(xi0,wv.z,acc[0][2]); acc[0][3]=fmaf(xi0,wv.w,acc[0][3]);
        acc[1][0]=fmaf(xi1,wv.x,acc[1][0]); acc[1][1]=fmaf(xi1,wv.y,acc[1][1]);
        acc[1][2]=fmaf(xi1,wv.z,acc[1][2]); acc[1][3]=fmaf(xi1,wv.w,acc[1][3]);
        acc[2][0]=fmaf(xi2,wv.x,acc[2][0]); acc[2][1]=fmaf(xi2,wv.y,acc[2][1]);
        acc[2][2]=fmaf(xi2,wv.z,acc[2][2]); acc[2][3]=fmaf(xi2,wv.w,acc[2][3]);
        acc[3][0]=fmaf(xi3,wv.x,acc[3][0]); acc[3][1]=fmaf(xi3,wv.y,acc[3][1]);
        acc[3][2]=fmaf(xi3,wv.z,acc[3][2]); acc[3][3]=fmaf(xi3,wv.w,acc[3][3]);
      }
    }
    #pragma unroll
    for (int q = 0; q < 4; ++q) {
      float4 o;
      o.x = acc[q][0]+bv.x; o.y = acc[q][1]+bv.y;
      o.z = acc[q][2]+bv.z; o.w = acc[q][3]+bv.w;
      *(float4*)&xp[(r0 + ty*4 + q)*NHID + jg] = o;
    }
    __syncthreads();
  }
}

// ---------------- persistent recurrent kernel ----------------
// MODE 0: x-proj precomputed in xp (hh-only loop).  MODE 1: r6 fallback
// (in-loop x-proj, Wx in regs) when ws_size can't hold xp.
template<int MODE>
__global__ __launch_bounds__(256, 1)
void rnn_persist_kernel(const float* __restrict__ x,
                        const float* __restrict__ Wih,
                        const float* __restrict__ bih,
                        const float* __restrict__ Whh,
                        const float* __restrict__ bhh,
                        const float* __restrict__ xp,
                        u32* __restrict__ hw)
{
  const int gj  = blockIdx.x >> 3;   // 0..15 hidden group
  const int gb  = blockIdx.x & 7;    // 0..7  batch group
  const int tid = threadIdx.x;
  const int jt  = tid >> 5;          // 0..7  j-tile (4 j's)
  const int bt  = (tid >> 4) & 1;    // 0..1  b-tile (4 b's)
  const int ks  = tid & 15;          // 0..15 k-split slot
  const int w   = tid >> 6, lane = tid & 63;

  __shared__ __align__(16) float hT[2][32][HT_ST];   // 35.8 KB, swizzled cols
  __shared__ __align__(16) float xTf[2][16][HT_ST];  // 17.9 KB (MODE 1 only)

  // ---- register-resident Whh tile ----
  float4 Wr[32];
  const int j0 = gj*32 + jt*4;
  #pragma unroll
  for (int kk = 0; kk < 32; ++kk) {
    const int k = (ks << 5) + kk;
    Wr[kk].x = Whh[(size_t)(j0+0)*NHID + k];
    Wr[kk].y = Whh[(size_t)(j0+1)*NHID + k];
    Wr[kk].z = Whh[(size_t)(j0+2)*NHID + k];
    Wr[kk].w = Whh[(size_t)(j0+3)*NHID + k];
  }
  float4 Wx[16];
  if constexpr (MODE == 1) {
    #pragma unroll
    for (int kk = 0; kk < 16; ++kk) {
      const int k = (ks << 4) + kk;
      Wx[kk].x = Wih[(size_t)(j0+0)*NIN + k];
      Wx[kk].y = Wih[(size_t)(j0+1)*NIN + k];
      Wx[kk].z = Wih[(size_t)(j0+2)*NIN + k];
      Wx[kk].w = Wih[(size_t)(j0+3)*NIN + k];
    }
  }
  const int jo = jt*4 + (ks >> 2);     // lane's output j (in block)
  const int bo = bt*4 + (ks & 3);      // and b (in group)
  const float bias = bih[gj*32 + jo] + bhh[gj*32 + jo];  // MODE1 (xp has it)
  const int   hsw  = swz((ks << 3) + (bt << 2));         // swizzled read col
  const size_t xpbase = ((size_t)(gb*8 + bo))*NHID + gj*32 + jo;

  // ---- prologue ----
  float xpC = 0.f;
  float4 xB0{}, xB1{};
  if constexpr (MODE == 0) {
    xpC = xp[xpbase];                            // xp(t=0)
  } else {
    const float4 x0a = XLOAD(0,0), x0b = XLOAD(0,1);
    xB0 = XLOAD(1,0); xB1 = XLOAD(1,1);
    {
      const int c = ((tid*2)&63) << 2, b = (tid*2) >> 6;
      const int kp = c & 15, xc = swz(((c>>4)<<3) + (b & 4)) + (b & 3);
      xTf[0][kp+0][xc]=x0a.x; xTf[0][kp+1][xc]=x0a.y;
      xTf[0][kp+2][xc]=x0a.z; xTf[0][kp+3][xc]=x0a.w;
      const int c1 = ((tid*2+1)&63) << 2, b1 = (tid*2+1) >> 6;
      const int kp1 = c1 & 15, xc1 = swz(((c1>>4)<<3) + (b1 & 4)) + (b1 & 3);
      xTf[0][kp1+0][xc1]=x0b.x; xTf[0][kp1+1][xc1]=x0b.y;
      xTf[0][kp1+2][xc1]=x0b.z; xTf[0][kp1+3][xc1]=x0b.w;
    }
  }
  u32x4 A[4], B[4];
  const u32* pp[4];
  #pragma unroll
  for (int s = 0; s < 4; ++s) {
    pp[s] = hw + ((((w<<2)+s)*GB + gb) << 9) + (lane<<3);
    A[s] = ld16_ic(pp[s]);  B[s] = ld16_ic(pp[s] + 4);
  }

  for (int t = 0; t < SEQ; ++t) {
    const int par = t & 1, par2 = par ^ 1;
    const u32 tg = (u32)t;

    // ---- check + stage h(t) -> hT[par] (swizzled); concurrent re-poll ----
    wait_vm0();
    u32 pend = 0xFu;
    int guard = 1 << 16;          // watchdog: bug => absmax-fail, not hang
    do {
      u32 nxt = 0;
      #pragma unroll
      for (int s = 0; s < 4; ++s) if (pend & (1u<<s)) {
        if (__all(tags8_ok(A[s], B[s], tg))) {
          const int i = (w<<2) + s;
          const int krow = lane >> 1;
          const int cb = swz((i<<3) + ((lane&1)<<2));
          float4 hv;
          hv.x = __uint_as_float((A[s].x<<16)|(A[s].y&0xffffu));
          hv.y = __uint_as_float((A[s].z<<16)|(A[s].w&0xffffu));
          hv.z = __uint_as_float((B[s].x<<16)|(B[s].y&0xffffu));
          hv.w = __uint_as_float((B[s].z<<16)|(B[s].w&0xffffu));
          *(float4*)&hT[par][krow][cb] = hv;
        } else nxt |= 1u<<s;
      }
      if (nxt) {
        #pragma unroll
        for (int s = 0; s < 4; ++s) if (nxt & (1u<<s)) {
          A[s] = ld16_ic(pp[s]);  B[s] = ld16_ic(pp[s] + 4);
        }
        wait_vm0();
      }
      pend = (--guard == 0) ? 0u : nxt;
    } while (pend);
    __syncthreads();

    // ---- next-step input: xp prefetch (MODE0) / xT stage + XLOAD (MODE1) --
    float xpN = 0.f;
    if constexpr (MODE == 0) {
      if (t + 1 < SEQ)
        xpN = xp[xpbase + (size_t)(t+1)*(BATCH*NHID)];
    } else {
      if (t + 1 < SEQ) {
        const int c = ((tid*2)&63) << 2, b = (tid*2) >> 6;
        const int kp = c & 15, xc = swz(((c>>4)<<3) + (b & 4)) + (b & 3);
        xTf[par2][kp+0][xc]=xB0.x; xTf[par2][kp+1][xc]=xB0.y;
        xTf[par2][kp+2][xc]=xB0.z; xTf[par2][kp+3][xc]=xB0.w;
        const int c1 = ((tid*2+1)&63) << 2, b1 = (tid*2+1) >> 6;
        const int kp1 = c1 & 15, xc1 = swz(((c1>>4)<<3) + (b1 & 4)) + (b1 & 3);
        xTf[par2][kp1+0][xc1]=xB1.x; xTf[par2][kp1+1][xc1]=xB1.y;
        xTf[par2][kp1+2][xc1]=xB1.z; xTf[par2][kp1+3][xc1]=xB1.w;
      }
      if (t + 2 < SEQ) { xB0 = XLOAD(t+2,0); xB1 = XLOAD(t+2,1); }
    }

    // ---- partial 4x4 tile: 32 (MODE0) or 48 (MODE1) b128 reads ----
    float a[16];
    #pragma unroll
    for (int i = 0; i < 16; ++i) a[i] = 0.f;
    #pragma unroll
    for (int kk = 0; kk < 32; ++kk) {
      const float4 hv = *(const float4*)&hT[par][kk][hsw];
      FMA16(Wr[kk], hv);
    }
    if constexpr (MODE == 1) {
      #pragma unroll
      for (int kk = 0; kk < 16; ++kk) {
        const float4 xv = *(const float4*)&xTf[par][kk][hsw];
        FMA16(Wx[kk], xv);
      }
    }

    // ---- butterfly k-reduction over 16 ks-lanes ----
    #pragma unroll
    for (int bb = 0; bb < 4; ++bb) {
      const int d = 1 << bb, n = 16 >> bb;
      const bool hi = (ks >> bb) & 1;
      float tt[16];
      #pragma unroll
      for (int i = 0; i < n; ++i) tt[i] = __shfl_xor(a[i], d, 16);
      #pragma unroll
      for (int i = 0; i < n/2; ++i)
        a[i] = hi ? (a[2*i+1] + tt[2*i+1]) : (a[2*i] + tt[2*i]);
    }
    const float hnew = tanhf(a[0] + ((MODE == 0) ? xpC : bias));

    // ---- publish h(t+1) ----
    {
      const u32 bits = __float_as_uint(hnew);
      const u32 tag  = (u32)(t+1) << 16;
      u32x2 pv; pv.x = tag | (bits >> 16); pv.y = tag | (bits & 0xffffu);
      const int m = jo*8 + bo;
      st8_ic(hw + par2*WORDS_PER_PAR + ((gj*GB+gb)<<9) + (m<<1), pv);
    }

    // ---- issue polls for t+1 ----
    if (t + 1 < SEQ) {
      const u32* nb = hw + par2*WORDS_PER_PAR;
      #pragma unroll
      for (int s = 0; s < 4; ++s) {
        pp[s] = nb + ((((w<<2)+s)*GB + gb) << 9) + (lane<<3);
        A[s] = ld16_ic(pp[s]);  B[s] = ld16_ic(pp[s] + 4);
      }
    }
    if constexpr (MODE == 0) xpC = xpN;
  }
}

// h_final = h(2048), parity 0, wire format
__global__ __launch_bounds__(NOUT, 1)
void rnn_out_kernel(const u32* __restrict__ hw,
                    const float* __restrict__ Who,
                    const float* __restrict__ bho,
                    float* __restrict__ out)
{
  const int b = blockIdx.x;    // 64
  const int o = threadIdx.x;   // 128
  __shared__ __align__(16) float hB[NHID];
  for (int k = o; k < NHID; k += NOUT) {
    const int slice = (k >> 5)*GB + (b >> 3);
    const int m     = ((k & 31) << 3) + (b & 7);
    const u32 hi = hw[(slice << 9) + (m << 1)];
    const u32 lo = hw[(slice << 9) + (m << 1) + 1];
    hB[k] = __uint_as_float((hi << 16) | (lo & 0xffffu));
  }
  __syncthreads();
  const float* wr = Who + (size_t)o*NHID;
  float a0=0.f,a1=0.f,a2=0.f,a3=0.f;
  for (int k = 0; k < NHID; k += 4) {
    const float4 wv = *(const float4*)&wr[k];
    a0 = fmaf(wv.x, hB[k  ], a0);
    a1 = fmaf(wv.y, hB[k+1], a1);
    a2 = fmaf(wv.z, hB[k+2], a2);
    a3 = fmaf(wv.w, hB[k+3], a3);
  }
  out[(size_t)b*NOUT + o] = (a0+a1)+(a2+a3) + bho[o];
}

extern "C" void kernel_launch(void* const* d_in, const int* in_sizes, int n_in,
                              void* d_out, int out_size, void* d_ws, size_t ws_size,
                              hipStream_t stream)
{
  const float* x   = (const float*)d_in[0];
  const float* Wih = (const float*)d_in[1];
  const float* bih = (const float*)d_in[2];
  const float* Whh = (const float*)d_in[3];
  const float* bhh = (const float*)d_in[4];
  const float* Who = (const float*)d_in[5];
  const float* bho = (const float*)d_in[6];
  float* out = (float*)d_out;
  u32*   hw  = (u32*)d_ws;                       // wire at base (both modes)
  float* xp  = (float*)((char*)d_ws + WIRE_BYTES);

  // zero wire buffer (tag0|0 == h(0)=0); deterministic graph replay
  hipMemsetAsync(d_ws, 0, WIRE_BYTES, stream);

  if (ws_size >= WIRE_BYTES + XP_BYTES) {
    xproj_kernel<<<dim3(2048), dim3(256), 0, stream>>>(x, Wih, bih, bhh, xp);
    rnn_persist_kernel<0><<<dim3(GB*GJ), dim3(256), 0, stream>>>(
        x, Wih, bih, Whh, bhh, xp, hw);
  } else {
    rnn_persist_kernel<1><<<dim3(GB*GJ), dim3(256), 0, stream>>>(
        x, Wih, bih, Whh, bhh, xp, hw);
  }
  rnn_out_kernel<<<dim3(BATCH), dim3(NOUT), 0, stream>>>(hw, Who, bho, out);
}